// Round 16
// baseline (334.758 us; speedup 1.0000x reference)
//
#include <hip/hip_runtime.h>
#include <hip/hip_bf16.h>
#include <float.h>

#define BATCH 8
#define CDIM 64
#define NPTS 4096
#define KNN 20
#define KSEL 32
#define BUFCAP 128
#define BN_EPS 1e-5f
#define NEG_SLOPE 0.2f

typedef __attribute__((ext_vector_type(8))) short short8;
typedef __attribute__((ext_vector_type(4))) float float4v;
typedef unsigned short ushort;
typedef unsigned int uint;
typedef unsigned long long ull;

__device__ __forceinline__ ushort f2bf(float f) {
    uint u = __float_as_uint(f);
    u += 0x7FFF + ((u >> 16) & 1);            // round-to-nearest-even
    return (ushort)(u >> 16);
}
__device__ __forceinline__ int mbcnt64(ull m) {
    int c = __builtin_amdgcn_mbcnt_lo((uint)m, 0);
    return __builtin_amdgcn_mbcnt_hi((uint)(m >> 32), c);
}

// Find 33rd-smallest key in buf[0..cnt), compact keys < K33 to front,
// set cnt to kept count (==32 when cnt>=33; keys distinct). Returns K33.
// Requires cnt <= 128 (two elements per lane).
__device__ __forceinline__ uint select33_truncate(uint* __restrict__ buf,
                                                  int& cnt, int lane) {
    uint e0 = 0xFFFFFFFFu, e1 = 0xFFFFFFFFu;
    if (lane < cnt) e0 = buf[lane];
    if (64 + lane < cnt) e1 = buf[64 + lane];
    uint p = 0;
    for (int bit = 31; bit >= 0; --bit) {
        uint t = p | (1u << bit);
        ull mA = __ballot(e0 < t);
        ull mB = __ballot(e1 < t);
        if (__popcll(mA) + __popcll(mB) < 33) p = t;   // uniform
    }
    ull mA = __ballot(e0 < p);
    ull mB = __ballot(e1 < p);
    int pA = __popcll(mA);
    int r0 = mbcnt64(mA);
    int r1 = pA + mbcnt64(mB);
    if (e0 < p) buf[r0] = e0;
    if (e1 < p) buf[r1] = e1;
    cnt = pA + __popcll(mB);
    return p;
}

// Streaming append of one candidate column (key = 20-bit dist | 12-bit idx).
// All control conditions are wave-uniform (ballot results / per-row scalars).
__device__ __forceinline__ void scan_append(float dwv, float base, int idx,
                                            uint& tau, int& cnt,
                                            uint* __restrict__ buf, int lane) {
    float dval = fmaxf(fmaf(-2.f, dwv, base), 0.f);
    uint key = (__float_as_uint(dval) & 0xFFFFF000u) | (uint)idx;
    ull mask = __ballot(key < tau);
    if (mask) {
        int c = __popcll(mask);
        if (cnt + c > BUFCAP) {
            tau = select33_truncate(buf, cnt, lane);
            mask = __ballot(key < tau);
            c = __popcll(mask);
        }
        if (c) {
            int rank = mbcnt64(mask);
            if (key < tau) buf[cnt + rank] = key;
            cnt += c;
        }
    }
}

// ===========================================================================
// XCD swizzle (all kernels): b = blockIdx & 7 maps every block of batch b to
// XCD b (round-robin dispatch). Proven R13: k_knn FETCH 17.2 -> 2.3 MB.
// ===========================================================================

// ---------------------------------------------------------------------------
// K1: fused prep+pz (+ S1/S2 zeroing by block 0; memset dispatch deleted —
// stream order guarantees zeros land before k_gather's atomics).
// ---------------------------------------------------------------------------
__global__ void __launch_bounds__(256) k_ppz(
        const float* __restrict__ x, const float* __restrict__ W,
        float* __restrict__ xt, ushort* __restrict__ xh,
        float* __restrict__ sq,
        float* __restrict__ pt, float* __restrict__ zt,
        float* __restrict__ S1) {
    __shared__ float xs[64][65];      // [n_local][channel]
    __shared__ float sqred[4][64];

    if (blockIdx.x == 0 && threadIdx.x < 128)
        S1[threadIdx.x] = 0.f;        // zeros S1[0..63] and S2[0..63]

    int b  = blockIdx.x & 7;          // batch -> XCD
    int n0 = (blockIdx.x >> 3) << 6;
    int lane = threadIdx.x & 63;
    int w = threadIdx.x >> 6;
    int row = b * NPTS + n0 + lane;

    const float* xb = x + (size_t)b * CDIM * NPTS + (n0 + lane);
    float v[16]; ushort h[16];
    float accq = 0.f;
    #pragma unroll
    for (int j = 0; j < 16; ++j) {
        float tv = xb[((w << 4) + j) * NPTS];   // coalesced across lane
        v[j] = tv;
        accq = fmaf(tv, tv, accq);
        h[j] = f2bf(tv);
        xs[lane][(w << 4) + j] = tv;
    }
    {
        float4* xtv = (float4*)(xt + ((size_t)row << 6) + (w << 4));
        #pragma unroll
        for (int q = 0; q < 4; ++q)
            xtv[q] = make_float4(v[q*4], v[q*4+1], v[q*4+2], v[q*4+3]);
        uint4* xhp = (uint4*)(xh + ((size_t)row << 6) + (w << 4));
        uint4 p0, p1;
        p0.x = (uint)h[0] | ((uint)h[1] << 16);
        p0.y = (uint)h[2] | ((uint)h[3] << 16);
        p0.z = (uint)h[4] | ((uint)h[5] << 16);
        p0.w = (uint)h[6] | ((uint)h[7] << 16);
        p1.x = (uint)h[8] | ((uint)h[9] << 16);
        p1.y = (uint)h[10] | ((uint)h[11] << 16);
        p1.z = (uint)h[12] | ((uint)h[13] << 16);
        p1.w = (uint)h[14] | ((uint)h[15] << 16);
        xhp[0] = p0; xhp[1] = p1;
    }
    sqred[w][lane] = accq;
    __syncthreads();
    if (w == 0)
        sq[row] = sqred[0][lane] + sqred[1][lane] +
                  sqred[2][lane] + sqred[3][lane];

    size_t rowoff = ((size_t)row) << 6;
    float acc1[16], acc2[16];
    #pragma unroll
    for (int i = 0; i < 16; ++i) { acc1[i] = 0.f; acc2[i] = 0.f; }
    #pragma unroll
    for (int cg = 0; cg < 4; ++cg) {
        float xv[16];
        #pragma unroll
        for (int j = 0; j < 16; ++j)
            xv[j] = xs[lane][(cg << 4) + j];
        #pragma unroll
        for (int oi = 0; oi < 16; ++oi) {
            int o = (w << 4) + oi;
            const float* wr = W + o * 128 + cg * 16;
            float a1 = acc1[oi], a2 = acc2[oi];
            #pragma unroll
            for (int j = 0; j < 16; ++j) {
                a1 = fmaf(wr[j],      xv[j], a1);
                a2 = fmaf(wr[64 + j], xv[j], a2);
            }
            acc1[oi] = a1; acc2[oi] = a2;
        }
    }
    float4* pv = (float4*)(pt + rowoff + (w << 4));
    float4* zv = (float4*)(zt + rowoff + (w << 4));
    #pragma unroll
    for (int q = 0; q < 4; ++q) {
        pv[q] = make_float4(acc1[q*4], acc1[q*4+1], acc1[q*4+2], acc1[q*4+3]);
        zv[q] = make_float4(acc2[q*4]   - acc1[q*4],
                            acc2[q*4+1] - acc1[q*4+1],
                            acc2[q*4+2] - acc1[q*4+2],
                            acc2[q*4+3] - acc1[q*4+3]);
    }
}

// ---------------------------------------------------------------------------
// K3: k_knn unchanged from R13 (155.9 us floor; XCD-swizzled, FETCH 2.3 MB).
// ---------------------------------------------------------------------------
__global__ void __launch_bounds__(256, 8) k_knn(
        const ushort* __restrict__ xh,
        const float* __restrict__ sq, ushort* __restrict__ knn32) {
    __shared__ float dw[2][64][20];       // [parity][cand][rows 0..15], 10 KB
    __shared__ uint rowbuf[16 * BUFCAP];  // 4 waves x 4 rows x 128, 8.2 KB

    int tid  = threadIdx.x;
    int t    = tid >> 6;              // wave 0..3
    int lane = tid & 63;
    int b    = blockIdx.x & 7;        // batch -> XCD
    int r0   = (blockIdx.x >> 3) << 4;    // block's 16 rows
    int col  = lane & 15;
    int quad = lane >> 4;

    // A fragments (chunk-invariant): row = r0 + col, k = quad*8 + j
    size_t arow = ((size_t)(b * NPTS + r0 + col)) << 6;
    short8 ah0 = *(const short8*)(xh + arow + quad * 8);
    short8 ah1 = *(const short8*)(xh + arow + 32 + quad * 8);

    const ushort* xhb = xh + (((size_t)b * NPTS) << 6);
    const float* sqb = sq + b * NPTS;
    // B-frag base for this lane: point (t*16+col) of chunk 0
    const ushort* fbase = xhb + (((size_t)((t << 4) + col)) << 6) + (quad << 3);

    uint tau[4];
    int cnt[4];
    float sqr[4];
    uint* wbuf = rowbuf + ((t << 2) * BUFCAP);
    #pragma unroll
    for (int r = 0; r < 4; ++r) {
        tau[r] = 0xFFFFFFFFu; cnt[r] = 0;
        sqr[r] = sqb[r0 + (t << 2) + r];
    }

    // prologue: frags + candidate-sq for chunk 0
    short8 fA0 = *(const short8*)fbase;
    short8 fA1 = *(const short8*)(fbase + 32);
    short8 fB0, fB1;
    float sv_cur = 0.f;               // sq of chunk (c-1) candidates at lane
    float sv_nxt = sqb[lane];         // sq of chunk c candidates at lane

    auto step = [&](int c, int q, short8& f0, short8& f1,
                    short8& nf0, short8& nf1) {
        // issue next-chunk frag + sq loads early (stay in flight over barrier)
        if (c + 1 < 64) {
            const ushort* p = fbase + (((size_t)(c + 1)) << 12);
            nf0 = *(const short8*)p;
            nf1 = *(const short8*)(p + 32);
        }
        float sv_tmp = (c + 1 < 64) ? sqb[((c + 1) << 6) + lane] : 0.f;

        // MFMA for chunk c: cands [16t,16t+16), rows [r0,r0+16)
        float4v acc = {0.f, 0.f, 0.f, 0.f};
        acc = __builtin_amdgcn_mfma_f32_16x16x32_bf16(ah0, f0, acc, 0, 0, 0);
        acc = __builtin_amdgcn_mfma_f32_16x16x32_bf16(ah1, f1, acc, 0, 0, 0);
        // acc[r] = dist(row 4*quad+r, cand 16t+col): single b128 store
        *(float4v*)&dw[q][(t << 4) + col][quad << 2] = acc;

        // scan chunk c-1 (dw parity q^1): one b128 read = this wave's 4 rows
        if (c > 0) {
            int m0 = (c - 1) << 6;
            float4v dv4 = *(const float4v*)&dw[q ^ 1][lane][t << 2];
            #pragma unroll
            for (int r = 0; r < 4; ++r) {
                scan_append(dv4[r], sv_cur + sqr[r], m0 + lane, tau[r], cnt[r],
                            wbuf + r * BUFCAP, lane);
            }
        }
        sv_cur = sv_nxt;
        sv_nxt = sv_tmp;

        // raw barrier: order LDS (dw, rowbuf) only; vmem stays in flight
        __builtin_amdgcn_sched_barrier(0);
        asm volatile("s_waitcnt lgkmcnt(0)" ::: "memory");
        __builtin_amdgcn_s_barrier();
        __builtin_amdgcn_sched_barrier(0);
    };

    for (int c = 0; c < 64; c += 2) {
        step(c,     0, fA0, fA1, fB0, fB1);
        step(c + 1, 1, fB0, fB1, fA0, fA1);
    }

    // drain: scan chunk 63 (dw parity 1); loop's final barrier ordered it
    {
        int m0 = 63 << 6;
        float4v dv4 = *(const float4v*)&dw[1][lane][t << 2];
        #pragma unroll
        for (int r = 0; r < 4; ++r) {
            scan_append(dv4[r], sv_cur + sqr[r], m0 + lane, tau[r], cnt[r],
                        wbuf + r * BUFCAP, lane);
        }
    }

    // final extraction: exact key-top-32 per row
    #pragma unroll
    for (int r = 0; r < 4; ++r) {
        select33_truncate(wbuf + r * BUFCAP, cnt[r], lane);
        if (lane < KSEL) {
            uint e = wbuf[r * BUFCAP + lane];
            knn32[(size_t)(b * NPTS + r0 + (t << 2) + r) * KSEL + lane] =
                (ushort)(e & 0xFFFu);
        }
    }
}

// ---------------------------------------------------------------------------
// K3b: exact fp32 refinement (R13 verbatim) — TWO rows per wave, half-wave
// per row, np (dist,idx) tie rule, emit top-20 set.
// ---------------------------------------------------------------------------
__global__ void __launch_bounds__(256) k_refine(
        const float* __restrict__ xt, const float* __restrict__ sq,
        const ushort* __restrict__ knn32, int* __restrict__ idx20) {
    int b    = blockIdx.x & 7;        // batch -> XCD
    int j    = blockIdx.x >> 3;       // 0..511 within batch
    int lane = threadIdx.x & 63;
    int wv   = threadIdx.x >> 6;      // 0..3
    int half = lane >> 5;
    int sl   = lane & 31;
    int row  = (b << 12) + (j << 3) + (wv << 1) + half;  // global row
    int cand = knn32[(size_t)row * KSEL + sl];
    const float4* xc = (const float4*)(xt + ((size_t)((b << 12) + cand) << 6));
    const float4* xr = (const float4*)(xt + ((size_t)row << 6));
    float acc = 0.f;
    #pragma unroll
    for (int q = 0; q < 16; ++q) {
        float4 a = xr[q], c = xc[q];
        acc = fmaf(a.x, c.x, acc); acc = fmaf(a.y, c.y, acc);
        acc = fmaf(a.z, c.z, acc); acc = fmaf(a.w, c.w, acc);
    }
    float d = fmaf(-2.f, acc, sq[(b << 12) + cand]);
    int rank = 0;
    int base = half << 5;
    #pragma unroll
    for (int jj = 0; jj < KSEL; ++jj) {
        float dj = __shfl(d, base + jj);
        int   cj = __shfl(cand, base + jj);
        rank += ((dj < d) || (dj == d && cj < cand)) ? 1 : 0;
    }
    if (rank < KNN)
        idx20[(size_t)row * KNN + rank] = cand;
}

// ---------------------------------------------------------------------------
// K4: gather, grid split 4x -> 2x (1024 blocks, 32 points/block, 8/wave):
// 4 blocks/CU = 4 waves/SIMD doubles latency-hiding TLP on the 20-load
// gather chains (was 2 waves/SIMD at 512 blocks). Atomics only 2x (vs 4x
// for a full split). Per (b,n): max/min/sum/sumsq over k; write tmax/tmin
// = extremum + z (fp32); accumulate channel sums.
// ---------------------------------------------------------------------------
__global__ void __launch_bounds__(256) k_gather(
        const float* __restrict__ pt, const float* __restrict__ zt,
        const int* __restrict__ idxin,
        float* __restrict__ tmax, float* __restrict__ tmin,
        float* __restrict__ S1, float* __restrict__ S2) {
    __shared__ float red1[4][64];
    __shared__ float red2[4][64];
    int b  = blockIdx.x & 7;          // batch -> XCD
    int n0 = (blockIdx.x >> 3) << 5;  // 32 points per block
    int lane = threadIdx.x & 63;
    int w = threadIdx.x >> 6;
    float cs1 = 0.f, cs2 = 0.f;
    #pragma unroll 2
    for (int i = 0; i < 8; ++i) {
        int n = n0 + (w << 3) + i;
        int base = b * NPTS + n;
        int ibase = __builtin_amdgcn_readfirstlane(base * KNN);
        const int* ip = idxin + ibase;
        float mx = -FLT_MAX, mn = FLT_MAX, s1 = 0.f, s2 = 0.f;
        #pragma unroll
        for (int k = 0; k < KNN; ++k) {
            int colp = ip[k];                              // SGPR
            float v = pt[(((size_t)(b * NPTS + colp)) << 6) + lane]; // coalesced
            mx = fmaxf(mx, v); mn = fminf(mn, v);
            s1 += v; s2 = fmaf(v, v, s2);
        }
        float z = zt[(((size_t)base) << 6) + lane];
        tmax[(((size_t)base) << 6) + lane] = mx + z;
        tmin[(((size_t)base) << 6) + lane] = mn + z;
        cs1 += s1 + (float)KNN * z;
        cs2 += s2 + 2.f * z * s1 + (float)KNN * z * z;
    }
    red1[w][lane] = cs1;
    red2[w][lane] = cs2;
    __syncthreads();
    if (threadIdx.x < 64) {
        float t1 = red1[0][lane] + red1[1][lane] + red1[2][lane] + red1[3][lane];
        float t2 = red2[0][lane] + red2[1][lane] + red2[2][lane] + red2[3][lane];
        atomicAdd(&S1[lane], t1);
        atomicAdd(&S2[lane], t2);
    }
}

// ---------------------------------------------------------------------------
// K5: finalize (R9 arrangement + XCD swizzle): BN stats, affine + LeakyReLU,
// transpose to out [B,64,N] via LDS. (Kept at 64-point blocks: splitting
// would shrink the coalesced out-write span from 256B to 64B.)
// ---------------------------------------------------------------------------
__global__ void k_final(const float* __restrict__ tmax, const float* __restrict__ tmin,
                        const float* __restrict__ S1, const float* __restrict__ S2,
                        const float* __restrict__ gamma, const float* __restrict__ beta,
                        float* __restrict__ out) {
    __shared__ float smx[64][65];
    __shared__ float smn[64][65];
    int b  = blockIdx.x & 7;          // batch -> XCD
    int n0 = (blockIdx.x >> 3) << 6;
    int lane = threadIdx.x & 63;
    int w = threadIdx.x >> 6;
    #pragma unroll
    for (int i = 0; i < 16; ++i) {
        int nl = (i << 2) + w;
        size_t off = (((size_t)(b * NPTS + n0 + nl)) << 6) + lane;
        smx[nl][lane] = tmax[off];
        smn[nl][lane] = tmin[off];
    }
    __syncthreads();
    const float inv_cnt = 1.0f / ((float)BATCH * NPTS * KNN);
    #pragma unroll
    for (int i = 0; i < 16; ++i) {
        int o = (i << 2) + w;
        float s1 = S1[o], s2 = S2[o];
        float mean = s1 * inv_cnt;
        float var = fmaf(-mean, mean, s2 * inv_cnt);
        float rs = rsqrtf(var + BN_EPS);
        float sc = gamma[o] * rs;
        float sh = beta[o] - mean * sc;
        float tv = (sc >= 0.f) ? smx[lane][o] : smn[lane][o];
        float y = fmaf(tv, sc, sh);
        y = (y >= 0.f) ? y : NEG_SLOPE * y;
        out[((size_t)(b * 64 + o)) * NPTS + n0 + lane] = y;
    }
}

// ---------------------------------------------------------------------------
extern "C" void kernel_launch(void* const* d_in, const int* in_sizes, int n_in,
                              void* d_out, int out_size, void* d_ws, size_t ws_size,
                              hipStream_t stream) {
    const float* x     = (const float*)d_in[0];   // [8,64,4096]
    const float* W     = (const float*)d_in[1];   // [64,128]
    const float* gamma = (const float*)d_in[2];   // [64]
    const float* beta  = (const float*)d_in[3];   // [64]
    float* out = (float*)d_out;                   // [8,64,4096]

    float* ws = (float*)d_ws;
    const size_t SECT = (size_t)BATCH * NPTS * 64;      // 2,097,152
    float*  xt    = ws;
    float*  pt    = ws + SECT;
    float*  zt    = ws + 2 * SECT;
    float*  sq    = ws + 3 * SECT;                       // 32768 floats
    float*  S1    = ws + 3 * SECT + 32768;               // 64
    float*  S2    = S1 + 64;
    int*    idx20 = (int*)(S1 + 128);                    // 655,360 ints
    float*  uA    = ws + 3 * SECT + 32768 + 128 + 655360;
    // union A:
    //   phase 1 (ppz..refine): xh (SECT ushorts) | knn32 (B*N*32 ushorts)
    //   phase 2 (gather..final): tmx (SECT floats) | tmn (SECT floats)
    ushort* xh    = (ushort*)uA;                         // SECT ushorts
    ushort* knn32 = (ushort*)(uA + SECT / 2);            // B*N*32 ushorts
    float*  tmx   = uA;                                  // SECT floats
    float*  tmn   = uA + SECT;                           // SECT floats

    k_ppz   <<<dim3(BATCH * (NPTS / 64)), dim3(256), 0, stream>>>(x, W, xt, xh, sq, pt, zt, S1);
    k_knn   <<<dim3(BATCH * (NPTS / 16)), dim3(256), 0, stream>>>(xh, sq, knn32);
    k_refine<<<dim3((BATCH * NPTS) / 8), dim3(256), 0, stream>>>(xt, sq, knn32, idx20);
    k_gather<<<dim3(BATCH * (NPTS / 32)), dim3(256), 0, stream>>>(pt, zt, idx20, tmx, tmn, S1, S2);
    k_final <<<dim3(BATCH * (NPTS / 64)), dim3(256), 0, stream>>>(tmx, tmn, S1, S2, gamma, beta, out);
}

// Round 17
// 326.944 us; speedup vs baseline: 1.0239x; 1.0239x over previous
//
#include <hip/hip_runtime.h>
#include <hip/hip_bf16.h>
#include <float.h>

#define BATCH 8
#define CDIM 64
#define NPTS 4096
#define KNN 20
#define KSEL 32
#define BUFCAP 128
#define BN_EPS 1e-5f
#define NEG_SLOPE 0.2f

typedef __attribute__((ext_vector_type(8))) short short8;
typedef __attribute__((ext_vector_type(4))) float float4v;
typedef unsigned short ushort;
typedef unsigned int uint;
typedef unsigned long long ull;

__device__ __forceinline__ ushort f2bf(float f) {
    uint u = __float_as_uint(f);
    u += 0x7FFF + ((u >> 16) & 1);            // round-to-nearest-even
    return (ushort)(u >> 16);
}
__device__ __forceinline__ int mbcnt64(ull m) {
    int c = __builtin_amdgcn_mbcnt_lo((uint)m, 0);
    return __builtin_amdgcn_mbcnt_hi((uint)(m >> 32), c);
}

// Find 33rd-smallest key in buf[0..cnt), compact keys < K33 to front,
// set cnt to kept count (==32 when cnt>=33; keys distinct). Returns K33.
// Requires cnt <= 128 (two elements per lane).
__device__ __forceinline__ uint select33_truncate(uint* __restrict__ buf,
                                                  int& cnt, int lane) {
    uint e0 = 0xFFFFFFFFu, e1 = 0xFFFFFFFFu;
    if (lane < cnt) e0 = buf[lane];
    if (64 + lane < cnt) e1 = buf[64 + lane];
    uint p = 0;
    for (int bit = 31; bit >= 0; --bit) {
        uint t = p | (1u << bit);
        ull mA = __ballot(e0 < t);
        ull mB = __ballot(e1 < t);
        if (__popcll(mA) + __popcll(mB) < 33) p = t;   // uniform
    }
    ull mA = __ballot(e0 < p);
    ull mB = __ballot(e1 < p);
    int pA = __popcll(mA);
    int r0 = mbcnt64(mA);
    int r1 = pA + mbcnt64(mB);
    if (e0 < p) buf[r0] = e0;
    if (e1 < p) buf[r1] = e1;
    cnt = pA + __popcll(mB);
    return p;
}

// Streaming append of one candidate column (key = 20-bit dist | 12-bit idx).
// All control conditions are wave-uniform (ballot results / per-row scalars).
__device__ __forceinline__ void scan_append(float dwv, float base, int idx,
                                            uint& tau, int& cnt,
                                            uint* __restrict__ buf, int lane) {
    float dval = fmaxf(fmaf(-2.f, dwv, base), 0.f);
    uint key = (__float_as_uint(dval) & 0xFFFFF000u) | (uint)idx;
    ull mask = __ballot(key < tau);
    if (mask) {
        int c = __popcll(mask);
        if (cnt + c > BUFCAP) {
            tau = select33_truncate(buf, cnt, lane);
            mask = __ballot(key < tau);
            c = __popcll(mask);
        }
        if (c) {
            int rank = mbcnt64(mask);
            if (key < tau) buf[cnt + rank] = key;
            cnt += c;
        }
    }
}

// ===========================================================================
// XCD swizzle (all kernels): b = blockIdx & 7 maps every block of batch b to
// XCD b (round-robin dispatch). Proven R13: k_knn FETCH 17.2 -> 2.3 MB.
// ===========================================================================

// ---------------------------------------------------------------------------
// K1: fused prep+pz (+ S1/S2 zeroing by block 0; memset dispatch deleted —
// stream order guarantees zeros land before k_gather's atomics).
// ---------------------------------------------------------------------------
__global__ void __launch_bounds__(256) k_ppz(
        const float* __restrict__ x, const float* __restrict__ W,
        float* __restrict__ xt, ushort* __restrict__ xh,
        float* __restrict__ sq,
        float* __restrict__ pt, float* __restrict__ zt,
        float* __restrict__ S1) {
    __shared__ float xs[64][65];      // [n_local][channel]
    __shared__ float sqred[4][64];

    if (blockIdx.x == 0 && threadIdx.x < 128)
        S1[threadIdx.x] = 0.f;        // zeros S1[0..63] and S2[0..63]

    int b  = blockIdx.x & 7;          // batch -> XCD
    int n0 = (blockIdx.x >> 3) << 6;
    int lane = threadIdx.x & 63;
    int w = threadIdx.x >> 6;
    int row = b * NPTS + n0 + lane;

    const float* xb = x + (size_t)b * CDIM * NPTS + (n0 + lane);
    float v[16]; ushort h[16];
    float accq = 0.f;
    #pragma unroll
    for (int j = 0; j < 16; ++j) {
        float tv = xb[((w << 4) + j) * NPTS];   // coalesced across lane
        v[j] = tv;
        accq = fmaf(tv, tv, accq);
        h[j] = f2bf(tv);
        xs[lane][(w << 4) + j] = tv;
    }
    {
        float4* xtv = (float4*)(xt + ((size_t)row << 6) + (w << 4));
        #pragma unroll
        for (int q = 0; q < 4; ++q)
            xtv[q] = make_float4(v[q*4], v[q*4+1], v[q*4+2], v[q*4+3]);
        uint4* xhp = (uint4*)(xh + ((size_t)row << 6) + (w << 4));
        uint4 p0, p1;
        p0.x = (uint)h[0] | ((uint)h[1] << 16);
        p0.y = (uint)h[2] | ((uint)h[3] << 16);
        p0.z = (uint)h[4] | ((uint)h[5] << 16);
        p0.w = (uint)h[6] | ((uint)h[7] << 16);
        p1.x = (uint)h[8] | ((uint)h[9] << 16);
        p1.y = (uint)h[10] | ((uint)h[11] << 16);
        p1.z = (uint)h[12] | ((uint)h[13] << 16);
        p1.w = (uint)h[14] | ((uint)h[15] << 16);
        xhp[0] = p0; xhp[1] = p1;
    }
    sqred[w][lane] = accq;
    __syncthreads();
    if (w == 0)
        sq[row] = sqred[0][lane] + sqred[1][lane] +
                  sqred[2][lane] + sqred[3][lane];

    size_t rowoff = ((size_t)row) << 6;
    float acc1[16], acc2[16];
    #pragma unroll
    for (int i = 0; i < 16; ++i) { acc1[i] = 0.f; acc2[i] = 0.f; }
    #pragma unroll
    for (int cg = 0; cg < 4; ++cg) {
        float xv[16];
        #pragma unroll
        for (int j = 0; j < 16; ++j)
            xv[j] = xs[lane][(cg << 4) + j];
        #pragma unroll
        for (int oi = 0; oi < 16; ++oi) {
            int o = (w << 4) + oi;
            const float* wr = W + o * 128 + cg * 16;
            float a1 = acc1[oi], a2 = acc2[oi];
            #pragma unroll
            for (int j = 0; j < 16; ++j) {
                a1 = fmaf(wr[j],      xv[j], a1);
                a2 = fmaf(wr[64 + j], xv[j], a2);
            }
            acc1[oi] = a1; acc2[oi] = a2;
        }
    }
    float4* pv = (float4*)(pt + rowoff + (w << 4));
    float4* zv = (float4*)(zt + rowoff + (w << 4));
    #pragma unroll
    for (int q = 0; q < 4; ++q) {
        pv[q] = make_float4(acc1[q*4], acc1[q*4+1], acc1[q*4+2], acc1[q*4+3]);
        zv[q] = make_float4(acc2[q*4]   - acc1[q*4],
                            acc2[q*4+1] - acc1[q*4+1],
                            acc2[q*4+2] - acc1[q*4+2],
                            acc2[q*4+3] - acc1[q*4+3]);
    }
}

// ---------------------------------------------------------------------------
// K3: k_knn unchanged from R13 (155.9 us floor; XCD-swizzled, FETCH 2.3 MB).
// ---------------------------------------------------------------------------
__global__ void __launch_bounds__(256, 8) k_knn(
        const ushort* __restrict__ xh,
        const float* __restrict__ sq, ushort* __restrict__ knn32) {
    __shared__ float dw[2][64][20];       // [parity][cand][rows 0..15], 10 KB
    __shared__ uint rowbuf[16 * BUFCAP];  // 4 waves x 4 rows x 128, 8.2 KB

    int tid  = threadIdx.x;
    int t    = tid >> 6;              // wave 0..3
    int lane = tid & 63;
    int b    = blockIdx.x & 7;        // batch -> XCD
    int r0   = (blockIdx.x >> 3) << 4;    // block's 16 rows
    int col  = lane & 15;
    int quad = lane >> 4;

    // A fragments (chunk-invariant): row = r0 + col, k = quad*8 + j
    size_t arow = ((size_t)(b * NPTS + r0 + col)) << 6;
    short8 ah0 = *(const short8*)(xh + arow + quad * 8);
    short8 ah1 = *(const short8*)(xh + arow + 32 + quad * 8);

    const ushort* xhb = xh + (((size_t)b * NPTS) << 6);
    const float* sqb = sq + b * NPTS;
    // B-frag base for this lane: point (t*16+col) of chunk 0
    const ushort* fbase = xhb + (((size_t)((t << 4) + col)) << 6) + (quad << 3);

    uint tau[4];
    int cnt[4];
    float sqr[4];
    uint* wbuf = rowbuf + ((t << 2) * BUFCAP);
    #pragma unroll
    for (int r = 0; r < 4; ++r) {
        tau[r] = 0xFFFFFFFFu; cnt[r] = 0;
        sqr[r] = sqb[r0 + (t << 2) + r];
    }

    // prologue: frags + candidate-sq for chunk 0
    short8 fA0 = *(const short8*)fbase;
    short8 fA1 = *(const short8*)(fbase + 32);
    short8 fB0, fB1;
    float sv_cur = 0.f;               // sq of chunk (c-1) candidates at lane
    float sv_nxt = sqb[lane];         // sq of chunk c candidates at lane

    auto step = [&](int c, int q, short8& f0, short8& f1,
                    short8& nf0, short8& nf1) {
        // issue next-chunk frag + sq loads early (stay in flight over barrier)
        if (c + 1 < 64) {
            const ushort* p = fbase + (((size_t)(c + 1)) << 12);
            nf0 = *(const short8*)p;
            nf1 = *(const short8*)(p + 32);
        }
        float sv_tmp = (c + 1 < 64) ? sqb[((c + 1) << 6) + lane] : 0.f;

        // MFMA for chunk c: cands [16t,16t+16), rows [r0,r0+16)
        float4v acc = {0.f, 0.f, 0.f, 0.f};
        acc = __builtin_amdgcn_mfma_f32_16x16x32_bf16(ah0, f0, acc, 0, 0, 0);
        acc = __builtin_amdgcn_mfma_f32_16x16x32_bf16(ah1, f1, acc, 0, 0, 0);
        // acc[r] = dist(row 4*quad+r, cand 16t+col): single b128 store
        *(float4v*)&dw[q][(t << 4) + col][quad << 2] = acc;

        // scan chunk c-1 (dw parity q^1): one b128 read = this wave's 4 rows
        if (c > 0) {
            int m0 = (c - 1) << 6;
            float4v dv4 = *(const float4v*)&dw[q ^ 1][lane][t << 2];
            #pragma unroll
            for (int r = 0; r < 4; ++r) {
                scan_append(dv4[r], sv_cur + sqr[r], m0 + lane, tau[r], cnt[r],
                            wbuf + r * BUFCAP, lane);
            }
        }
        sv_cur = sv_nxt;
        sv_nxt = sv_tmp;

        // raw barrier: order LDS (dw, rowbuf) only; vmem stays in flight
        __builtin_amdgcn_sched_barrier(0);
        asm volatile("s_waitcnt lgkmcnt(0)" ::: "memory");
        __builtin_amdgcn_s_barrier();
        __builtin_amdgcn_sched_barrier(0);
    };

    for (int c = 0; c < 64; c += 2) {
        step(c,     0, fA0, fA1, fB0, fB1);
        step(c + 1, 1, fB0, fB1, fA0, fA1);
    }

    // drain: scan chunk 63 (dw parity 1); loop's final barrier ordered it
    {
        int m0 = 63 << 6;
        float4v dv4 = *(const float4v*)&dw[1][lane][t << 2];
        #pragma unroll
        for (int r = 0; r < 4; ++r) {
            scan_append(dv4[r], sv_cur + sqr[r], m0 + lane, tau[r], cnt[r],
                        wbuf + r * BUFCAP, lane);
        }
    }

    // final extraction: exact key-top-32 per row
    #pragma unroll
    for (int r = 0; r < 4; ++r) {
        select33_truncate(wbuf + r * BUFCAP, cnt[r], lane);
        if (lane < KSEL) {
            uint e = wbuf[r * BUFCAP + lane];
            knn32[(size_t)(b * NPTS + r0 + (t << 2) + r) * KSEL + lane] =
                (ushort)(e & 0xFFFu);
        }
    }
}

// ---------------------------------------------------------------------------
// K3b: exact fp32 refinement (R13 verbatim) — TWO rows per wave, half-wave
// per row, np (dist,idx) tie rule, emit top-20 set.
// ---------------------------------------------------------------------------
__global__ void __launch_bounds__(256) k_refine(
        const float* __restrict__ xt, const float* __restrict__ sq,
        const ushort* __restrict__ knn32, int* __restrict__ idx20) {
    int b    = blockIdx.x & 7;        // batch -> XCD
    int j    = blockIdx.x >> 3;       // 0..511 within batch
    int lane = threadIdx.x & 63;
    int wv   = threadIdx.x >> 6;      // 0..3
    int half = lane >> 5;
    int sl   = lane & 31;
    int row  = (b << 12) + (j << 3) + (wv << 1) + half;  // global row
    int cand = knn32[(size_t)row * KSEL + sl];
    const float4* xc = (const float4*)(xt + ((size_t)((b << 12) + cand) << 6));
    const float4* xr = (const float4*)(xt + ((size_t)row << 6));
    float acc = 0.f;
    #pragma unroll
    for (int q = 0; q < 16; ++q) {
        float4 a = xr[q], c = xc[q];
        acc = fmaf(a.x, c.x, acc); acc = fmaf(a.y, c.y, acc);
        acc = fmaf(a.z, c.z, acc); acc = fmaf(a.w, c.w, acc);
    }
    float d = fmaf(-2.f, acc, sq[(b << 12) + cand]);
    int rank = 0;
    int base = half << 5;
    #pragma unroll
    for (int jj = 0; jj < KSEL; ++jj) {
        float dj = __shfl(d, base + jj);
        int   cj = __shfl(cand, base + jj);
        rank += ((dj < d) || (dj == d && cj < cand)) ? 1 : 0;
    }
    if (rank < KNN)
        idx20[(size_t)row * KNN + rank] = cand;
}

// ---------------------------------------------------------------------------
// K4: gather (R9 arrangement + XCD swizzle + row-loop unroll 2): per (b,n)
// max/min/sum/sumsq over k; write tmax/tmin = extremum + z (fp32);
// accumulate channel sums. (R16 falsified the 2x grid split: per-block
// fixed costs outgrew the TLP gain — 512 blocks is the measured optimum.)
// ---------------------------------------------------------------------------
__global__ void k_gather(const float* __restrict__ pt, const float* __restrict__ zt,
                         const int* __restrict__ idxin,
                         float* __restrict__ tmax, float* __restrict__ tmin,
                         float* __restrict__ S1, float* __restrict__ S2) {
    __shared__ float red1[4][64];
    __shared__ float red2[4][64];
    int b  = blockIdx.x & 7;          // batch -> XCD
    int n0 = (blockIdx.x >> 3) << 6;
    int lane = threadIdx.x & 63;
    int w = threadIdx.x >> 6;
    float cs1 = 0.f, cs2 = 0.f;
    #pragma unroll 2
    for (int i = 0; i < 16; ++i) {
        int n = n0 + (w << 4) + i;
        int base = b * NPTS + n;
        int ibase = __builtin_amdgcn_readfirstlane(base * KNN);
        const int* ip = idxin + ibase;
        float mx = -FLT_MAX, mn = FLT_MAX, s1 = 0.f, s2 = 0.f;
        #pragma unroll
        for (int k = 0; k < KNN; ++k) {
            int colp = ip[k];                              // SGPR
            float v = pt[(((size_t)(b * NPTS + colp)) << 6) + lane]; // coalesced
            mx = fmaxf(mx, v); mn = fminf(mn, v);
            s1 += v; s2 = fmaf(v, v, s2);
        }
        float z = zt[(((size_t)base) << 6) + lane];
        tmax[(((size_t)base) << 6) + lane] = mx + z;
        tmin[(((size_t)base) << 6) + lane] = mn + z;
        cs1 += s1 + (float)KNN * z;
        cs2 += s2 + 2.f * z * s1 + (float)KNN * z * z;
    }
    red1[w][lane] = cs1;
    red2[w][lane] = cs2;
    __syncthreads();
    if (threadIdx.x < 64) {
        float t1 = red1[0][lane] + red1[1][lane] + red1[2][lane] + red1[3][lane];
        float t2 = red2[0][lane] + red2[1][lane] + red2[2][lane] + red2[3][lane];
        atomicAdd(&S1[lane], t1);
        atomicAdd(&S2[lane], t2);
    }
}

// ---------------------------------------------------------------------------
// K5: finalize (R9 arrangement + XCD swizzle): BN stats, affine + LeakyReLU,
// transpose to out [B,64,N] via LDS.
// ---------------------------------------------------------------------------
__global__ void k_final(const float* __restrict__ tmax, const float* __restrict__ tmin,
                        const float* __restrict__ S1, const float* __restrict__ S2,
                        const float* __restrict__ gamma, const float* __restrict__ beta,
                        float* __restrict__ out) {
    __shared__ float smx[64][65];
    __shared__ float smn[64][65];
    int b  = blockIdx.x & 7;          // batch -> XCD
    int n0 = (blockIdx.x >> 3) << 6;
    int lane = threadIdx.x & 63;
    int w = threadIdx.x >> 6;
    #pragma unroll
    for (int i = 0; i < 16; ++i) {
        int nl = (i << 2) + w;
        size_t off = (((size_t)(b * NPTS + n0 + nl)) << 6) + lane;
        smx[nl][lane] = tmax[off];
        smn[nl][lane] = tmin[off];
    }
    __syncthreads();
    const float inv_cnt = 1.0f / ((float)BATCH * NPTS * KNN);
    #pragma unroll
    for (int i = 0; i < 16; ++i) {
        int o = (i << 2) + w;
        float s1 = S1[o], s2 = S2[o];
        float mean = s1 * inv_cnt;
        float var = fmaf(-mean, mean, s2 * inv_cnt);
        float rs = rsqrtf(var + BN_EPS);
        float sc = gamma[o] * rs;
        float sh = beta[o] - mean * sc;
        float tv = (sc >= 0.f) ? smx[lane][o] : smn[lane][o];
        float y = fmaf(tv, sc, sh);
        y = (y >= 0.f) ? y : NEG_SLOPE * y;
        out[((size_t)(b * 64 + o)) * NPTS + n0 + lane] = y;
    }
}

// ---------------------------------------------------------------------------
extern "C" void kernel_launch(void* const* d_in, const int* in_sizes, int n_in,
                              void* d_out, int out_size, void* d_ws, size_t ws_size,
                              hipStream_t stream) {
    const float* x     = (const float*)d_in[0];   // [8,64,4096]
    const float* W     = (const float*)d_in[1];   // [64,128]
    const float* gamma = (const float*)d_in[2];   // [64]
    const float* beta  = (const float*)d_in[3];   // [64]
    float* out = (float*)d_out;                   // [8,64,4096]

    float* ws = (float*)d_ws;
    const size_t SECT = (size_t)BATCH * NPTS * 64;      // 2,097,152
    float*  xt    = ws;
    float*  pt    = ws + SECT;
    float*  zt    = ws + 2 * SECT;
    float*  sq    = ws + 3 * SECT;                       // 32768 floats
    float*  S1    = ws + 3 * SECT + 32768;               // 64
    float*  S2    = S1 + 64;
    int*    idx20 = (int*)(S1 + 128);                    // 655,360 ints
    float*  uA    = ws + 3 * SECT + 32768 + 128 + 655360;
    // union A:
    //   phase 1 (ppz..refine): xh (SECT ushorts) | knn32 (B*N*32 ushorts)
    //   phase 2 (gather..final): tmx (SECT floats) | tmn (SECT floats)
    ushort* xh    = (ushort*)uA;                         // SECT ushorts
    ushort* knn32 = (ushort*)(uA + SECT / 2);            // B*N*32 ushorts
    float*  tmx   = uA;                                  // SECT floats
    float*  tmn   = uA + SECT;                           // SECT floats

    k_ppz   <<<dim3(BATCH * (NPTS / 64)), dim3(256), 0, stream>>>(x, W, xt, xh, sq, pt, zt, S1);
    k_knn   <<<dim3(BATCH * (NPTS / 16)), dim3(256), 0, stream>>>(xh, sq, knn32);
    k_refine<<<dim3((BATCH * NPTS) / 8), dim3(256), 0, stream>>>(xt, sq, knn32, idx20);
    k_gather<<<dim3(BATCH * (NPTS / 64)), dim3(256), 0, stream>>>(pt, zt, idx20, tmx, tmn, S1, S2);
    k_final <<<dim3(BATCH * (NPTS / 64)), dim3(256), 0, stream>>>(tmx, tmn, S1, S2, gamma, beta, out);
}